// Round 1
// baseline (713.101 us; speedup 1.0000x reference)
//
#include <hip/hip_runtime.h>

typedef unsigned short u16;
typedef __attribute__((ext_vector_type(4))) float f32x4;
typedef __attribute__((ext_vector_type(8))) short s16x8;

constexpr int DMODEL = 1024;
constexpr int NH     = 16;
constexpr int DK     = 64;
constexpr int SEQ    = 4096;
constexpr int BATCH  = 2;
constexpr int BS     = BATCH * SEQ;     // 8192
constexpr int NX     = BS * DMODEL;     // 8,388,608
constexpr int NW     = DMODEL * DMODEL; // 1,048,576

__device__ __forceinline__ u16 f2bf(float f) {
  union { float f; unsigned u; } v; v.f = f;
  unsigned r = v.u + 0x7fffu + ((v.u >> 16) & 1u);
  return (u16)(r >> 16);
}
__device__ __forceinline__ float bf2f(u16 h) {
  union { unsigned u; float f; } v; v.u = ((unsigned)h) << 16;
  return v.f;
}
__device__ __forceinline__ void gload_lds16(const void* g, void* l) {
  __builtin_amdgcn_global_load_lds(
      (const __attribute__((address_space(1))) void*)g,
      (__attribute__((address_space(3))) void*)l, 16, 0, 0);
}

// ---------------- fp32 -> bf16 conversion for x and W[qkvo] ----------------
__global__ __launch_bounds__(256) void convert_all(
    const float* __restrict__ x, const float* __restrict__ wq,
    const float* __restrict__ wk, const float* __restrict__ wv,
    const float* __restrict__ wo, u16* __restrict__ xb, u16* __restrict__ Wb) {
  int t = blockIdx.x * 256 + threadIdx.x;
  int i = t * 4;
  const float* src; u16* dst;
  if (i < NX) { src = x + i; dst = xb + i; }
  else {
    int j = i - NX; int w = j >> 20; int jj = j & (NW - 1);
    src = (w == 0 ? wq : w == 1 ? wk : w == 2 ? wv : wo) + jj;
    dst = Wb + j;
  }
  float4 v = *reinterpret_cast<const float4*>(src);
  unsigned lo = (unsigned)f2bf(v.x) | ((unsigned)f2bf(v.y) << 16);
  unsigned hi = (unsigned)f2bf(v.z) | ((unsigned)f2bf(v.w) << 16);
  uint2 pk; pk.x = lo; pk.y = hi;
  *reinterpret_cast<uint2*>(dst) = pk;
}

// ---------------- 128x128 bf16 GEMM, C = A * B^T (B rows = output cols) ----
// EPI 0: scatter to Q(b,h,s,d) / K(b,h,s,d) / Vt(b,h,d,s) bf16
// EPI 1: fp32 row-major output
template <int EPI>
__global__ __launch_bounds__(256) void gemm128(
    const u16* __restrict__ A, const u16* __restrict__ B,
    u16* __restrict__ Qw, u16* __restrict__ Kw, u16* __restrict__ Vt,
    float* __restrict__ Co) {
  __shared__ u16 lA[128 * 32];
  __shared__ u16 lB[128 * 32];
  const int tid = threadIdx.x, w = tid >> 6, l = tid & 63;
  const int wr = w >> 1, wc = w & 1;
  const int m0 = blockIdx.y * 128, n0 = blockIdx.x * 128;
  constexpr int K = 1024;
  f32x4 acc[4][4] = {};
  const int li = l & 15, lg = l >> 4;
  const int srow = l >> 2, skc = (l & 3) * 8;
  for (int k0 = 0; k0 < K; k0 += 32) {
    __syncthreads();
#pragma unroll
    for (int cc = 0; cc < 2; ++cc) {
      const int c = 2 * w + cc;
      const int row = c * 16 + srow;
      gload_lds16(A + (size_t)(m0 + row) * K + k0 + skc, &lA[c * 512]);
      gload_lds16(B + (size_t)(n0 + row) * K + k0 + skc, &lB[c * 512]);
    }
    __syncthreads();
    s16x8 af[4], bfr[4];
#pragma unroll
    for (int i = 0; i < 4; ++i)
      af[i] = *reinterpret_cast<const s16x8*>(&lA[(wr * 64 + i * 16 + li) * 32 + lg * 8]);
#pragma unroll
    for (int j = 0; j < 4; ++j)
      bfr[j] = *reinterpret_cast<const s16x8*>(&lB[(wc * 64 + j * 16 + li) * 32 + lg * 8]);
#pragma unroll
    for (int i = 0; i < 4; ++i)
#pragma unroll
      for (int j = 0; j < 4; ++j)
        acc[i][j] = __builtin_amdgcn_mfma_f32_16x16x32_bf16(af[i], bfr[j], acc[i][j], 0, 0, 0);
  }
#pragma unroll
  for (int i = 0; i < 4; ++i) {
    const int mbase = m0 + wr * 64 + i * 16 + lg * 4;
#pragma unroll
    for (int j = 0; j < 4; ++j) {
      const int n = n0 + wc * 64 + j * 16 + li;
      if (EPI == 0) {
        const int which = n >> 10, nn = n & 1023, h = nn >> 6, d = nn & 63;
#pragma unroll
        for (int r = 0; r < 4; ++r) {
          const int m = mbase + r, b = m >> 12, s = m & (SEQ - 1);
          const int bh = b * NH + h;
          const u16 val = f2bf(acc[i][j][r]);
          if (which == 0)      Qw[((size_t)bh * SEQ + s) * DK + d] = val;
          else if (which == 1) Kw[((size_t)bh * SEQ + s) * DK + d] = val;
          else                 Vt[((size_t)bh * DK + d) * SEQ + s] = val;
        }
      } else {
#pragma unroll
        for (int r = 0; r < 4; ++r)
          Co[(size_t)(mbase + r) * DMODEL + n] = acc[i][j][r];
      }
    }
  }
}

// ---------------- RoPE in-place on Q and K (bf16, interleaved pairs) -------
__global__ __launch_bounds__(256) void rope_qk(u16* __restrict__ Qw, u16* __restrict__ Kw,
                                               const int* __restrict__ pos) {
  const int TOT = BATCH * NH * SEQ * 32;  // pairs per tensor
  int t = blockIdx.x * 256 + threadIdx.x;
  u16* arr = (t < TOT) ? Qw : Kw;
  int p = (t < TOT) ? t : t - TOT;
  const int i = p & 31;
  const int s = (p >> 5) & (SEQ - 1);
  const int bh = p >> 17;
  // inv_freq = 10000^(-i/32) = exp(-i * ln(10000)/32), accurate expf
  const float inv = expf(-(float)i * 0.28782313662425574f);
  const float ang = (float)pos[s] * inv;
  float sn, cs;
  sincosf(ang, &sn, &cs);
  u16* ptr = arr + ((size_t)bh * SEQ + s) * DK + 2 * i;
  unsigned v = *reinterpret_cast<unsigned*>(ptr);
  float xe = bf2f((u16)(v & 0xffffu)), xo = bf2f((u16)(v >> 16));
  float oe = xe * cs - xo * sn;
  float oo = xe * sn + xo * cs;
  *reinterpret_cast<unsigned*>(ptr) = (unsigned)f2bf(oe) | ((unsigned)f2bf(oo) << 16);
}

// ---------------- causal flash attention ----------------------------------
// grid (S/128, B*H), 4 waves/block, wave owns 32 q rows; KBLK=64
__global__ __launch_bounds__(256) void attn_kernel(
    const u16* __restrict__ Qw, const u16* __restrict__ Kw,
    const u16* __restrict__ Vt, u16* __restrict__ Ob) {
  __shared__ u16 Pb[4][32][72];  // per-wave P buffer, padded stride 72
  const int tid = threadIdx.x, w = tid >> 6, l = tid & 63;
  const int li = l & 15, lg = l >> 4;
  const int bh = blockIdx.y;
  const int q0 = blockIdx.x * 128 + w * 32;
  const u16* Qh = Qw + (size_t)bh * SEQ * DK;
  const u16* Kh = Kw + (size_t)bh * SEQ * DK;
  const u16* Vh = Vt + (size_t)bh * DK * SEQ;

  s16x8 aq[2][2];
#pragma unroll
  for (int qs = 0; qs < 2; ++qs)
#pragma unroll
    for (int ds = 0; ds < 2; ++ds)
      aq[qs][ds] = *reinterpret_cast<const s16x8*>(
          &Qh[(size_t)(q0 + qs * 16 + li) * DK + ds * 32 + lg * 8]);

  f32x4 o[2][4] = {};
  float mrun[2][4], lrun[2][4];
#pragma unroll
  for (int qs = 0; qs < 2; ++qs)
#pragma unroll
    for (int r = 0; r < 4; ++r) { mrun[qs][r] = -1e30f; lrun[qs][r] = 0.f; }

  const int kend = q0 + 32;
  for (int kt = 0; kt < kend; kt += 64) {
    f32x4 sc[2][4];
#pragma unroll
    for (int ks = 0; ks < 4; ++ks) {
      const u16* kr = &Kh[(size_t)(kt + ks * 16 + li) * DK + lg * 8];
      s16x8 bk0 = *reinterpret_cast<const s16x8*>(kr);
      s16x8 bk1 = *reinterpret_cast<const s16x8*>(kr + 32);
#pragma unroll
      for (int qs = 0; qs < 2; ++qs) {
        f32x4 z = {0.f, 0.f, 0.f, 0.f};
        z = __builtin_amdgcn_mfma_f32_16x16x32_bf16(aq[qs][0], bk0, z, 0, 0, 0);
        z = __builtin_amdgcn_mfma_f32_16x16x32_bf16(aq[qs][1], bk1, z, 0, 0, 0);
        sc[qs][ks] = z;
      }
    }
    const bool needMask = (kt + 63 > q0);
#pragma unroll
    for (int qs = 0; qs < 2; ++qs)
#pragma unroll
      for (int ks = 0; ks < 4; ++ks)
#pragma unroll
        for (int r = 0; r < 4; ++r) {
          float v = sc[qs][ks][r] * 0.125f;
          if (needMask && (kt + ks * 16 + li > q0 + qs * 16 + lg * 4 + r)) v = -1e30f;
          sc[qs][ks][r] = v;
        }
#pragma unroll
    for (int qs = 0; qs < 2; ++qs)
#pragma unroll
      for (int r = 0; r < 4; ++r) {
        float mx = fmaxf(fmaxf(sc[qs][0][r], sc[qs][1][r]), fmaxf(sc[qs][2][r], sc[qs][3][r]));
#pragma unroll
        for (int d = 8; d >= 1; d >>= 1) mx = fmaxf(mx, __shfl_xor(mx, d, 64));
        const float mnew = fmaxf(mrun[qs][r], mx);
        const float fs = __expf(mrun[qs][r] - mnew);
        float rs = 0.f;
#pragma unroll
        for (int ks = 0; ks < 4; ++ks) {
          float p = __expf(sc[qs][ks][r] - mnew);
          sc[qs][ks][r] = p; rs += p;
        }
#pragma unroll
        for (int d = 8; d >= 1; d >>= 1) rs += __shfl_xor(rs, d, 64);
        lrun[qs][r] = lrun[qs][r] * fs + rs;
        mrun[qs][r] = mnew;
#pragma unroll
        for (int ds = 0; ds < 4; ++ds) o[qs][ds][r] *= fs;
      }
    // P (C-layout) -> LDS -> A-layout fragments
#pragma unroll
    for (int qs = 0; qs < 2; ++qs)
#pragma unroll
      for (int ks = 0; ks < 4; ++ks)
#pragma unroll
        for (int r = 0; r < 4; ++r)
          Pb[w][qs * 16 + lg * 4 + r][ks * 16 + li] = f2bf(sc[qs][ks][r]);
    s16x8 ap[2][2];
#pragma unroll
    for (int qs = 0; qs < 2; ++qs)
#pragma unroll
      for (int kp = 0; kp < 2; ++kp)
        ap[qs][kp] = *reinterpret_cast<const s16x8*>(&Pb[w][qs * 16 + li][kp * 32 + lg * 8]);
#pragma unroll
    for (int ds = 0; ds < 4; ++ds) {
      const u16* vr = &Vh[(size_t)(ds * 16 + li) * SEQ + kt + lg * 8];
      s16x8 bv0 = *reinterpret_cast<const s16x8*>(vr);
      s16x8 bv1 = *reinterpret_cast<const s16x8*>(vr + 32);
#pragma unroll
      for (int qs = 0; qs < 2; ++qs) {
        o[qs][ds] = __builtin_amdgcn_mfma_f32_16x16x32_bf16(ap[qs][0], bv0, o[qs][ds], 0, 0, 0);
        o[qs][ds] = __builtin_amdgcn_mfma_f32_16x16x32_bf16(ap[qs][1], bv1, o[qs][ds], 0, 0, 0);
      }
    }
  }
  const int b = bh >> 4, h = bh & 15;
#pragma unroll
  for (int qs = 0; qs < 2; ++qs)
#pragma unroll
    for (int r = 0; r < 4; ++r) {
      const float inv = 1.f / lrun[qs][r];
      const int s = q0 + qs * 16 + lg * 4 + r;
      u16* orow = Ob + ((size_t)(b * SEQ + s)) * DMODEL + h * DK;
#pragma unroll
      for (int ds = 0; ds < 4; ++ds)
        orow[ds * 16 + li] = f2bf(o[qs][ds][r] * inv);
    }
}

extern "C" void kernel_launch(void* const* d_in, const int* in_sizes, int n_in,
                              void* d_out, int out_size, void* d_ws, size_t ws_size,
                              hipStream_t stream) {
  const float* x  = (const float*)d_in[0];
  const int*  pos = (const int*)d_in[1];
  const float* wq = (const float*)d_in[2];
  const float* wk = (const float*)d_in[3];
  const float* wv = (const float*)d_in[4];
  const float* wo = (const float*)d_in[5];
  float* out = (float*)d_out;

  u16* Wb = (u16*)d_ws;               // 4*NW bf16 (Wq|Wk|Wv|Wo)
  u16* xb = Wb + 4 * (size_t)NW;      // NX bf16
  u16* Qw = xb + (size_t)NX;          // (b,h,s,d)
  u16* Kw = Qw + (size_t)NX;          // (b,h,s,d)
  u16* Vt = Kw + (size_t)NX;          // (b,h,d,s)
  u16* Ab = xb;                       // reuse x-bf16 region for attn output

  convert_all<<<(NX + 4 * NW) / 4 / 256, 256, 0, stream>>>(x, wq, wk, wv, wo, xb, Wb);
  gemm128<0><<<dim3(24, 64), 256, 0, stream>>>(xb, Wb, Qw, Kw, Vt, nullptr);
  rope_qk<<<2 * (BATCH * NH * SEQ * 32) / 256, 256, 0, stream>>>(Qw, Kw, pos);
  attn_kernel<<<dim3(SEQ / 128, BATCH * NH), 256, 0, stream>>>(Qw, Kw, Vt, Ab);
  gemm128<1><<<dim3(8, 64), 256, 0, stream>>>(Ab, Wb + 3 * (size_t)NW, nullptr, nullptr, nullptr, out);
}

// Round 2
// 491.836 us; speedup vs baseline: 1.4499x; 1.4499x over previous
//
#include <hip/hip_runtime.h>

typedef unsigned short u16;
typedef __attribute__((ext_vector_type(4))) float f32x4;
typedef __attribute__((ext_vector_type(8))) short s16x8;

constexpr int DMODEL = 1024;
constexpr int NH     = 16;
constexpr int DK     = 64;
constexpr int SEQ    = 4096;
constexpr int BATCH  = 2;
constexpr int BS     = BATCH * SEQ;     // 8192
constexpr int NX     = BS * DMODEL;     // 8,388,608
constexpr int NW     = DMODEL * DMODEL; // 1,048,576

__device__ __forceinline__ u16 f2bf(float f) {
  union { float f; unsigned u; } v; v.f = f;
  unsigned r = v.u + 0x7fffu + ((v.u >> 16) & 1u);
  return (u16)(r >> 16);
}
__device__ __forceinline__ float bf2f(u16 h) {
  union { unsigned u; float f; } v; v.u = ((unsigned)h) << 16;
  return v.f;
}
__device__ __forceinline__ void gload_lds16(const void* g, void* l) {
  __builtin_amdgcn_global_load_lds(
      (const __attribute__((address_space(1))) void*)g,
      (__attribute__((address_space(3))) void*)l, 16, 0, 0);
}

// ---------------- fp32 -> bf16 conversion for x and W[qkvo] ----------------
__global__ __launch_bounds__(256) void convert_all(
    const float* __restrict__ x, const float* __restrict__ wq,
    const float* __restrict__ wk, const float* __restrict__ wv,
    const float* __restrict__ wo, u16* __restrict__ xb, u16* __restrict__ Wb) {
  int t = blockIdx.x * 256 + threadIdx.x;
  int i = t * 4;
  const float* src; u16* dst;
  if (i < NX) { src = x + i; dst = xb + i; }
  else {
    int j = i - NX; int w = j >> 20; int jj = j & (NW - 1);
    src = (w == 0 ? wq : w == 1 ? wk : w == 2 ? wv : wo) + jj;
    dst = Wb + j;
  }
  float4 v = *reinterpret_cast<const float4*>(src);
  unsigned lo = (unsigned)f2bf(v.x) | ((unsigned)f2bf(v.y) << 16);
  unsigned hi = (unsigned)f2bf(v.z) | ((unsigned)f2bf(v.w) << 16);
  uint2 pk; pk.x = lo; pk.y = hi;
  *reinterpret_cast<uint2*>(dst) = pk;
}

// ---------------- 128x128 bf16 GEMM, C = A * B^T (B rows = output cols) ----
template <int EPI>
__global__ __launch_bounds__(256) void gemm128(
    const u16* __restrict__ A, const u16* __restrict__ B,
    u16* __restrict__ Qw, u16* __restrict__ Kw, u16* __restrict__ Vt,
    float* __restrict__ Co) {
  __shared__ u16 lA[128 * 32];
  __shared__ u16 lB[128 * 32];
  const int tid = threadIdx.x, w = tid >> 6, l = tid & 63;
  const int wr = w >> 1, wc = w & 1;
  const int m0 = blockIdx.y * 128, n0 = blockIdx.x * 128;
  constexpr int K = 1024;
  f32x4 acc[4][4] = {};
  const int li = l & 15, lg = l >> 4;
  const int srow = l >> 2, skc = (l & 3) * 8;
  for (int k0 = 0; k0 < K; k0 += 32) {
    __syncthreads();
#pragma unroll
    for (int cc = 0; cc < 2; ++cc) {
      const int c = 2 * w + cc;
      const int row = c * 16 + srow;
      gload_lds16(A + (size_t)(m0 + row) * K + k0 + skc, &lA[c * 512]);
      gload_lds16(B + (size_t)(n0 + row) * K + k0 + skc, &lB[c * 512]);
    }
    __syncthreads();
    s16x8 af[4], bfr[4];
#pragma unroll
    for (int i = 0; i < 4; ++i)
      af[i] = *reinterpret_cast<const s16x8*>(&lA[(wr * 64 + i * 16 + li) * 32 + lg * 8]);
#pragma unroll
    for (int j = 0; j < 4; ++j)
      bfr[j] = *reinterpret_cast<const s16x8*>(&lB[(wc * 64 + j * 16 + li) * 32 + lg * 8]);
#pragma unroll
    for (int i = 0; i < 4; ++i)
#pragma unroll
      for (int j = 0; j < 4; ++j)
        acc[i][j] = __builtin_amdgcn_mfma_f32_16x16x32_bf16(af[i], bfr[j], acc[i][j], 0, 0, 0);
  }
#pragma unroll
  for (int i = 0; i < 4; ++i) {
    const int mbase = m0 + wr * 64 + i * 16 + lg * 4;
#pragma unroll
    for (int j = 0; j < 4; ++j) {
      const int n = n0 + wc * 64 + j * 16 + li;
      if (EPI == 0) {
        const int which = n >> 10, nn = n & 1023, h = nn >> 6, d = nn & 63;
#pragma unroll
        for (int r = 0; r < 4; ++r) {
          const int m = mbase + r, b = m >> 12, s = m & (SEQ - 1);
          const int bh = b * NH + h;
          const u16 val = f2bf(acc[i][j][r]);
          if (which == 0)      Qw[((size_t)bh * SEQ + s) * DK + d] = val;
          else if (which == 1) Kw[((size_t)bh * SEQ + s) * DK + d] = val;
          else                 Vt[((size_t)bh * DK + d) * SEQ + s] = val;
        }
      } else {
#pragma unroll
        for (int r = 0; r < 4; ++r)
          Co[(size_t)(mbase + r) * DMODEL + n] = acc[i][j][r];
      }
    }
  }
}

// ---------------- RoPE in-place on Q and K (bf16, interleaved pairs) -------
__global__ __launch_bounds__(256) void rope_qk(u16* __restrict__ Qw, u16* __restrict__ Kw,
                                               const int* __restrict__ pos) {
  const int TOT = BATCH * NH * SEQ * 32;  // pairs per tensor
  int t = blockIdx.x * 256 + threadIdx.x;
  u16* arr = (t < TOT) ? Qw : Kw;
  int p = (t < TOT) ? t : t - TOT;
  const int i = p & 31;
  const int s = (p >> 5) & (SEQ - 1);
  const int bh = p >> 17;
  const float inv = expf(-(float)i * 0.28782313662425574f);
  const float ang = (float)pos[s] * inv;
  float sn, cs;
  sincosf(ang, &sn, &cs);
  u16* ptr = arr + ((size_t)bh * SEQ + s) * DK + 2 * i;
  unsigned v = *reinterpret_cast<unsigned*>(ptr);
  float xe = bf2f((u16)(v & 0xffffu)), xo = bf2f((u16)(v >> 16));
  float oe = xe * cs - xo * sn;
  float oo = xe * sn + xo * cs;
  *reinterpret_cast<unsigned*>(ptr) = (unsigned)f2bf(oe) | ((unsigned)f2bf(oo) << 16);
}

// ---------------- causal flash attention, LDS-staged double-buffered -------
// 1D grid of 1024 blocks; block -> (bh, bx) via XCD-chunked remap, reversed
// bx for load balance. 4 waves/block, each owns 32 q rows of a 128-row tile.
// K/V tiles (64x64 bf16 = 8KB each) staged via global_load_lds (pre-swizzled
// source, XOR-swizzled read: byte ^= (row&7)<<4) and double-buffered: the
// next tile's 8 loads are issued before compute, drained by vmcnt(0) at the
// next iteration's barrier.
__global__ __launch_bounds__(256) void attn_kernel(
    const u16* __restrict__ Qw, const u16* __restrict__ Kw,
    const u16* __restrict__ Vt, u16* __restrict__ Ob) {
  __shared__ u16 Kb[2][4096];
  __shared__ u16 Vb[2][4096];
  __shared__ u16 Pb[4][32][76];  // stride 152B: lg-groups hit disjoint banks
  const int tid = threadIdx.x, w = tid >> 6, l = tid & 63;
  const int li = l & 15, lg = l >> 4;
  const int id = blockIdx.x;
  const int g = (id & 7) * 128 + (id >> 3);   // XCD-chunked
  const int bh = g >> 5;                      // 4 heads per XCD chunk
  const int bx = 31 - (g & 31);               // heavy blocks first
  const int q0 = bx * 128 + w * 32;
  const int ntiles = 2 * bx + 2;
  const u16* Qh = Qw + (size_t)bh * SEQ * DK;
  const u16* Kh = Kw + (size_t)bh * SEQ * DK;
  const u16* Vh = Vt + (size_t)bh * DK * SEQ;

  // staging geometry: thread tid loads 16B chunk; row = chunk/8 of the 64x128B
  // tile, source column pre-swizzled so a linear LDS write + swizzled read match
  const int row0  = tid >> 3;                        // 0..31 (g=0), +32 (g=1)
  const int scol0 = ((tid & 7) * 16) ^ ((row0 & 7) << 4);

  // Q fragments, resident in registers
  s16x8 aq[2][2];
#pragma unroll
  for (int qs = 0; qs < 2; ++qs)
#pragma unroll
    for (int ds = 0; ds < 2; ++ds)
      aq[qs][ds] = *reinterpret_cast<const s16x8*>(
          &Qh[(size_t)(q0 + qs * 16 + li) * DK + ds * 32 + lg * 8]);

  f32x4 o[2][4] = {};
  float mrun[2][4], lrun[2][4];
#pragma unroll
  for (int qs = 0; qs < 2; ++qs)
#pragma unroll
    for (int r = 0; r < 4; ++r) { mrun[qs][r] = -1e30f; lrun[qs][r] = 0.f; }

  auto stage = [&](int buf, int kt) {
    const char* ksrc = (const char*)Kh + (size_t)(kt + row0) * 128 + scol0;
    char* kdst = (char*)&Kb[buf][0] + (size_t)w * 1024;
    gload_lds16(ksrc, kdst);
    gload_lds16(ksrc + 32 * 128, kdst + 4096);
    const char* vsrc = (const char*)Vh + (size_t)row0 * (SEQ * 2) + kt * 2 + scol0;
    char* vdst = (char*)&Vb[buf][0] + (size_t)w * 1024;
    gload_lds16(vsrc, vdst);
    gload_lds16(vsrc + (size_t)32 * SEQ * 2, vdst + 4096);
  };

  stage(0, 0);
  int kt = 0;
  for (int t = 0; t < ntiles; ++t, kt += 64) {
    asm volatile("s_waitcnt vmcnt(0)" ::: "memory");  // current buf staged
    __builtin_amdgcn_s_barrier();
    __builtin_amdgcn_sched_barrier(0);
    {
      const int ktn = (t + 1 < ntiles) ? kt + 64 : 0;  // dummy re-stage on last
      stage((t + 1) & 1, ktn);
    }
    if (kt < q0 + 32) {  // skip fully-masked tiles for this wave
      const int cur = t & 1;
      f32x4 sc[2][4];
#pragma unroll
      for (int ks = 0; ks < 4; ++ks) {
        const int R = ks * 16 + li;
        const char* kbase = (const char*)&Kb[cur][0] + R * 128;
        const int sw = (R & 7) << 4;
        s16x8 bk0 = *reinterpret_cast<const s16x8*>(kbase + ((lg * 16) ^ sw));
        s16x8 bk1 = *reinterpret_cast<const s16x8*>(kbase + (((64 + lg * 16)) ^ sw));
#pragma unroll
        for (int qs = 0; qs < 2; ++qs) {
          f32x4 z = {0.f, 0.f, 0.f, 0.f};
          z = __builtin_amdgcn_mfma_f32_16x16x32_bf16(aq[qs][0], bk0, z, 0, 0, 0);
          z = __builtin_amdgcn_mfma_f32_16x16x32_bf16(aq[qs][1], bk1, z, 0, 0, 0);
          sc[qs][ks] = z;
        }
      }
      const bool needMask = (kt + 63 > q0);
      if (needMask) {
#pragma unroll
        for (int qs = 0; qs < 2; ++qs)
#pragma unroll
          for (int ks = 0; ks < 4; ++ks)
#pragma unroll
            for (int r = 0; r < 4; ++r) {
              float v = sc[qs][ks][r] * 0.125f;
              if (kt + ks * 16 + li > q0 + qs * 16 + lg * 4 + r) v = -1e30f;
              sc[qs][ks][r] = v;
            }
      } else {
#pragma unroll
        for (int qs = 0; qs < 2; ++qs)
#pragma unroll
          for (int ks = 0; ks < 4; ++ks)
#pragma unroll
            for (int r = 0; r < 4; ++r) sc[qs][ks][r] *= 0.125f;
      }
#pragma unroll
      for (int qs = 0; qs < 2; ++qs)
#pragma unroll
        for (int r = 0; r < 4; ++r) {
          float mx = fmaxf(fmaxf(sc[qs][0][r], sc[qs][1][r]), fmaxf(sc[qs][2][r], sc[qs][3][r]));
#pragma unroll
          for (int d = 8; d >= 1; d >>= 1) mx = fmaxf(mx, __shfl_xor(mx, d, 64));
          const float mnew = fmaxf(mrun[qs][r], mx);
          const float fs = __expf(mrun[qs][r] - mnew);
          float rs = 0.f;
#pragma unroll
          for (int ks = 0; ks < 4; ++ks) {
            float p = __expf(sc[qs][ks][r] - mnew);
            sc[qs][ks][r] = p; rs += p;
          }
#pragma unroll
          for (int d = 8; d >= 1; d >>= 1) rs += __shfl_xor(rs, d, 64);
          lrun[qs][r] = lrun[qs][r] * fs + rs;
          mrun[qs][r] = mnew;
#pragma unroll
          for (int ds = 0; ds < 4; ++ds) o[qs][ds][r] *= fs;
        }
      // P (C-layout) -> LDS -> A-layout fragments
#pragma unroll
      for (int qs = 0; qs < 2; ++qs)
#pragma unroll
        for (int ks = 0; ks < 4; ++ks)
#pragma unroll
          for (int r = 0; r < 4; ++r)
            Pb[w][qs * 16 + lg * 4 + r][ks * 16 + li] = f2bf(sc[qs][ks][r]);
      s16x8 ap[2][2];
#pragma unroll
      for (int qs = 0; qs < 2; ++qs)
#pragma unroll
        for (int kp = 0; kp < 2; ++kp)
          ap[qs][kp] = *reinterpret_cast<const s16x8*>(&Pb[w][qs * 16 + li][kp * 32 + lg * 8]);
#pragma unroll
      for (int ds = 0; ds < 4; ++ds) {
        const int R = ds * 16 + li;
        const char* vbase = (const char*)&Vb[cur][0] + R * 128;
        const int sw = (R & 7) << 4;
        s16x8 bv0 = *reinterpret_cast<const s16x8*>(vbase + ((lg * 16) ^ sw));
        s16x8 bv1 = *reinterpret_cast<const s16x8*>(vbase + (((64 + lg * 16)) ^ sw));
#pragma unroll
        for (int qs = 0; qs < 2; ++qs) {
          o[qs][ds] = __builtin_amdgcn_mfma_f32_16x16x32_bf16(ap[qs][0], bv0, o[qs][ds], 0, 0, 0);
          o[qs][ds] = __builtin_amdgcn_mfma_f32_16x16x32_bf16(ap[qs][1], bv1, o[qs][ds], 0, 0, 0);
        }
      }
    }
  }
  const int b = bh >> 4, h = bh & 15;
#pragma unroll
  for (int qs = 0; qs < 2; ++qs)
#pragma unroll
    for (int r = 0; r < 4; ++r) {
      const float inv = 1.f / lrun[qs][r];
      const int s = q0 + qs * 16 + lg * 4 + r;
      u16* orow = Ob + ((size_t)(b * SEQ + s)) * DMODEL + h * DK;
#pragma unroll
      for (int ds = 0; ds < 4; ++ds)
        orow[ds * 16 + li] = f2bf(o[qs][ds][r] * inv);
    }
}

extern "C" void kernel_launch(void* const* d_in, const int* in_sizes, int n_in,
                              void* d_out, int out_size, void* d_ws, size_t ws_size,
                              hipStream_t stream) {
  const float* x  = (const float*)d_in[0];
  const int*  pos = (const int*)d_in[1];
  const float* wq = (const float*)d_in[2];
  const float* wk = (const float*)d_in[3];
  const float* wv = (const float*)d_in[4];
  const float* wo = (const float*)d_in[5];
  float* out = (float*)d_out;

  u16* Wb = (u16*)d_ws;               // 4*NW bf16 (Wq|Wk|Wv|Wo)
  u16* xb = Wb + 4 * (size_t)NW;      // NX bf16
  u16* Qw = xb + (size_t)NX;          // (b,h,s,d)
  u16* Kw = Qw + (size_t)NX;          // (b,h,s,d)
  u16* Vt = Kw + (size_t)NX;          // (b,h,d,s)
  u16* Ab = xb;                       // reuse x-bf16 region for attn output

  convert_all<<<(NX + 4 * NW) / 4 / 256, 256, 0, stream>>>(x, wq, wk, wv, wo, xb, Wb);
  gemm128<0><<<dim3(24, 64), 256, 0, stream>>>(xb, Wb, Qw, Kw, Vt, nullptr);
  rope_qk<<<2 * (BATCH * NH * SEQ * 32) / 256, 256, 0, stream>>>(Qw, Kw, pos);
  attn_kernel<<<1024, 256, 0, stream>>>(Qw, Kw, Vt, Ab);
  gemm128<1><<<dim3(8, 64), 256, 0, stream>>>(Ab, Wb + 3 * (size_t)NW, nullptr, nullptr, nullptr, out);
}

// Round 3
// 396.603 us; speedup vs baseline: 1.7980x; 1.2401x over previous
//
#include <hip/hip_runtime.h>

typedef unsigned short u16;
typedef __attribute__((ext_vector_type(4))) float f32x4;
typedef __attribute__((ext_vector_type(8))) short s16x8;

constexpr int DMODEL = 1024;
constexpr int NH     = 16;
constexpr int DK     = 64;
constexpr int SEQ    = 4096;
constexpr int BATCH  = 2;
constexpr int BS     = BATCH * SEQ;     // 8192
constexpr int NX     = BS * DMODEL;     // 8,388,608
constexpr int NW     = DMODEL * DMODEL; // 1,048,576

__device__ __forceinline__ u16 f2bf(float f) {
  union { float f; unsigned u; } v; v.f = f;
  unsigned r = v.u + 0x7fffu + ((v.u >> 16) & 1u);
  return (u16)(r >> 16);
}
__device__ __forceinline__ float bf2f(u16 h) {
  union { unsigned u; float f; } v; v.u = ((unsigned)h) << 16;
  return v.f;
}
__device__ __forceinline__ void gload_lds16(const void* g, void* l) {
  __builtin_amdgcn_global_load_lds(
      (const __attribute__((address_space(1))) void*)g,
      (__attribute__((address_space(3))) void*)l, 16, 0, 0);
}

// ---------------- fp32 -> bf16 conversion for x and W[qkvo] ----------------
__global__ __launch_bounds__(256) void convert_all(
    const float* __restrict__ x, const float* __restrict__ wq,
    const float* __restrict__ wk, const float* __restrict__ wv,
    const float* __restrict__ wo, u16* __restrict__ xb, u16* __restrict__ Wb) {
  int t = blockIdx.x * 256 + threadIdx.x;
  int i = t * 4;
  const float* src; u16* dst;
  if (i < NX) { src = x + i; dst = xb + i; }
  else {
    int j = i - NX; int w = j >> 20; int jj = j & (NW - 1);
    src = (w == 0 ? wq : w == 1 ? wk : w == 2 ? wv : wo) + jj;
    dst = Wb + j;
  }
  float4 v = *reinterpret_cast<const float4*>(src);
  unsigned lo = (unsigned)f2bf(v.x) | ((unsigned)f2bf(v.y) << 16);
  unsigned hi = (unsigned)f2bf(v.z) | ((unsigned)f2bf(v.w) << 16);
  uint2 pk; pk.x = lo; pk.y = hi;
  *reinterpret_cast<uint2*>(dst) = pk;
}

// ---------------- 128x128 bf16 GEMM, C = A * B^T (B rows = output cols) ----
template <int EPI>
__global__ __launch_bounds__(256) void gemm128(
    const u16* __restrict__ A, const u16* __restrict__ B,
    u16* __restrict__ Qw, u16* __restrict__ Kw, u16* __restrict__ Vt,
    float* __restrict__ Co) {
  __shared__ u16 lA[128 * 32];
  __shared__ u16 lB[128 * 32];
  const int tid = threadIdx.x, w = tid >> 6, l = tid & 63;
  const int wr = w >> 1, wc = w & 1;
  const int m0 = blockIdx.y * 128, n0 = blockIdx.x * 128;
  constexpr int K = 1024;
  f32x4 acc[4][4] = {};
  const int li = l & 15, lg = l >> 4;
  const int srow = l >> 2, skc = (l & 3) * 8;
  for (int k0 = 0; k0 < K; k0 += 32) {
    __syncthreads();
#pragma unroll
    for (int cc = 0; cc < 2; ++cc) {
      const int c = 2 * w + cc;
      const int row = c * 16 + srow;
      gload_lds16(A + (size_t)(m0 + row) * K + k0 + skc, &lA[c * 512]);
      gload_lds16(B + (size_t)(n0 + row) * K + k0 + skc, &lB[c * 512]);
    }
    __syncthreads();
    s16x8 af[4], bfr[4];
#pragma unroll
    for (int i = 0; i < 4; ++i)
      af[i] = *reinterpret_cast<const s16x8*>(&lA[(wr * 64 + i * 16 + li) * 32 + lg * 8]);
#pragma unroll
    for (int j = 0; j < 4; ++j)
      bfr[j] = *reinterpret_cast<const s16x8*>(&lB[(wc * 64 + j * 16 + li) * 32 + lg * 8]);
#pragma unroll
    for (int i = 0; i < 4; ++i)
#pragma unroll
      for (int j = 0; j < 4; ++j)
        acc[i][j] = __builtin_amdgcn_mfma_f32_16x16x32_bf16(af[i], bfr[j], acc[i][j], 0, 0, 0);
  }
#pragma unroll
  for (int i = 0; i < 4; ++i) {
    const int mbase = m0 + wr * 64 + i * 16 + lg * 4;
#pragma unroll
    for (int j = 0; j < 4; ++j) {
      const int n = n0 + wc * 64 + j * 16 + li;
      if (EPI == 0) {
        const int which = n >> 10, nn = n & 1023, h = nn >> 6, d = nn & 63;
#pragma unroll
        for (int r = 0; r < 4; ++r) {
          const int m = mbase + r, b = m >> 12, s = m & (SEQ - 1);
          const int bh = b * NH + h;
          const u16 val = f2bf(acc[i][j][r]);
          if (which == 0)      Qw[((size_t)bh * SEQ + s) * DK + d] = val;
          else if (which == 1) Kw[((size_t)bh * SEQ + s) * DK + d] = val;
          else                 Vt[((size_t)bh * DK + d) * SEQ + s] = val;
        }
      } else {
#pragma unroll
        for (int r = 0; r < 4; ++r)
          Co[(size_t)(mbase + r) * DMODEL + n] = acc[i][j][r];
      }
    }
  }
}

// ---------------- RoPE in-place on Q and K (bf16, interleaved pairs) -------
__global__ __launch_bounds__(256) void rope_qk(u16* __restrict__ Qw, u16* __restrict__ Kw,
                                               const int* __restrict__ pos) {
  const int TOT = BATCH * NH * SEQ * 32;  // pairs per tensor
  int t = blockIdx.x * 256 + threadIdx.x;
  u16* arr = (t < TOT) ? Qw : Kw;
  int p = (t < TOT) ? t : t - TOT;
  const int i = p & 31;
  const int s = (p >> 5) & (SEQ - 1);
  const int bh = p >> 17;
  const float inv = expf(-(float)i * 0.28782313662425574f);
  const float ang = (float)pos[s] * inv;
  float sn, cs;
  sincosf(ang, &sn, &cs);
  u16* ptr = arr + ((size_t)bh * SEQ + s) * DK + 2 * i;
  unsigned v = *reinterpret_cast<unsigned*>(ptr);
  float xe = bf2f((u16)(v & 0xffffu)), xo = bf2f((u16)(v >> 16));
  float oe = xe * cs - xo * sn;
  float oo = xe * sn + xo * cs;
  *reinterpret_cast<unsigned*>(ptr) = (unsigned)f2bf(oe) | ((unsigned)f2bf(oo) << 16);
}

// ---------------- causal flash attention, LDS-staged, paired q-tiles -------
// 512 blocks, each processes TWO 128-row q-tiles (heavy tA=31-j, then light
// tB=j) sequentially -> uniform 66 k-tile iterations per block, 2 blocks/CU
// resident for the whole kernel (zero tail). K/V double-buffer pipeline runs
// uninterrupted across the phase boundary.
__global__ __launch_bounds__(256) void attn_kernel(
    const u16* __restrict__ Qw, const u16* __restrict__ Kw,
    const u16* __restrict__ Vt, u16* __restrict__ Ob) {
  __shared__ u16 Kb[2][4096];
  __shared__ u16 Vb[2][4096];
  __shared__ u16 Pb[4][32][76];  // stride 152B: lg-groups hit disjoint banks
  const int tid = threadIdx.x, w = tid >> 6, l = tid & 63;
  const int li = l & 15, lg = l >> 4;
  const int id = blockIdx.x;
  const int g = (id & 7) * 64 + (id >> 3);    // XCD-chunked (64 blocks/XCD)
  const int bh = g >> 4;                      // 4 heads per XCD chunk
  const int j  = g & 15;                      // pair index
  const int tA = 31 - j, tB = j;              // heavy first
  const int nA = 2 * tA + 2, nB = 2 * tB + 2; // 66 total iterations
  const u16* Qh = Qw + (size_t)bh * SEQ * DK;
  const u16* Kh = Kw + (size_t)bh * SEQ * DK;
  const u16* Vh = Vt + (size_t)bh * DK * SEQ;
  const int b = bh >> 4, h = bh & 15;

  const int row0  = tid >> 3;
  const int scol0 = ((tid & 7) * 16) ^ ((row0 & 7) << 4);

  s16x8 aq[2][2];
  f32x4 o[2][4];
  float mrun[2][4], lrun[2][4];

  auto loadQ = [&](int q0) {
#pragma unroll
    for (int qs = 0; qs < 2; ++qs)
#pragma unroll
      for (int ds = 0; ds < 2; ++ds)
        aq[qs][ds] = *reinterpret_cast<const s16x8*>(
            &Qh[(size_t)(q0 + qs * 16 + li) * DK + ds * 32 + lg * 8]);
  };
  auto resetState = [&]() {
#pragma unroll
    for (int qs = 0; qs < 2; ++qs)
#pragma unroll
      for (int r = 0; r < 4; ++r) {
        mrun[qs][r] = -1e30f; lrun[qs][r] = 0.f;
#pragma unroll
        for (int ds = 0; ds < 4; ++ds) o[qs][ds][r] = 0.f;
      }
  };
  auto writeO = [&](int q0) {
#pragma unroll
    for (int qs = 0; qs < 2; ++qs)
#pragma unroll
      for (int r = 0; r < 4; ++r) {
        const float inv = 1.f / lrun[qs][r];
        const int s = q0 + qs * 16 + lg * 4 + r;
        u16* orow = Ob + ((size_t)(b * SEQ + s)) * DMODEL + h * DK;
#pragma unroll
        for (int ds = 0; ds < 4; ++ds)
          orow[ds * 16 + li] = f2bf(o[qs][ds][r] * inv);
      }
  };
  auto stage = [&](int buf, int kt) {
    const char* ksrc = (const char*)Kh + (size_t)(kt + row0) * 128 + scol0;
    char* kdst = (char*)&Kb[buf][0] + (size_t)w * 1024;
    gload_lds16(ksrc, kdst);
    gload_lds16(ksrc + 32 * 128, kdst + 4096);
    const char* vsrc = (const char*)Vh + (size_t)row0 * (SEQ * 2) + kt * 2 + scol0;
    char* vdst = (char*)&Vb[buf][0] + (size_t)w * 1024;
    gload_lds16(vsrc, vdst);
    gload_lds16(vsrc + (size_t)32 * SEQ * 2, vdst + 4096);
  };

  int q0 = tA * 128 + w * 32;
  loadQ(q0);
  resetState();
  stage(0, 0);
  int kt = 0;
  const int ntot = nA + nB;
  for (int it = 0; it < ntot; ++it) {
    asm volatile("s_waitcnt vmcnt(0)" ::: "memory");  // current buf staged
    __builtin_amdgcn_s_barrier();
    __builtin_amdgcn_sched_barrier(0);
    const int itn = it + 1;
    const int ktn = (itn < nA) ? 64 * itn : (itn < ntot ? 64 * (itn - nA) : 0);
    stage(itn & 1, ktn);
    if (kt < q0 + 32) {  // skip fully-masked tiles for this wave
      const int cur = it & 1;
      f32x4 sc[2][4];
#pragma unroll
      for (int ks = 0; ks < 4; ++ks) {
        const int R = ks * 16 + li;
        const char* kbase = (const char*)&Kb[cur][0] + R * 128;
        const int sw = (R & 7) << 4;
        s16x8 bk0 = *reinterpret_cast<const s16x8*>(kbase + ((lg * 16) ^ sw));
        s16x8 bk1 = *reinterpret_cast<const s16x8*>(kbase + (((64 + lg * 16)) ^ sw));
#pragma unroll
        for (int qs = 0; qs < 2; ++qs) {
          f32x4 z = {0.f, 0.f, 0.f, 0.f};
          z = __builtin_amdgcn_mfma_f32_16x16x32_bf16(aq[qs][0], bk0, z, 0, 0, 0);
          z = __builtin_amdgcn_mfma_f32_16x16x32_bf16(aq[qs][1], bk1, z, 0, 0, 0);
          sc[qs][ks] = z;
        }
      }
      const bool needMask = (kt + 63 > q0);
      if (needMask) {
#pragma unroll
        for (int qs = 0; qs < 2; ++qs)
#pragma unroll
          for (int ks = 0; ks < 4; ++ks)
#pragma unroll
            for (int r = 0; r < 4; ++r) {
              float v = sc[qs][ks][r] * 0.125f;
              if (kt + ks * 16 + li > q0 + qs * 16 + lg * 4 + r) v = -1e30f;
              sc[qs][ks][r] = v;
            }
      } else {
#pragma unroll
        for (int qs = 0; qs < 2; ++qs)
#pragma unroll
          for (int ks = 0; ks < 4; ++ks)
#pragma unroll
            for (int r = 0; r < 4; ++r) sc[qs][ks][r] *= 0.125f;
      }
#pragma unroll
      for (int qs = 0; qs < 2; ++qs)
#pragma unroll
        for (int r = 0; r < 4; ++r) {
          float mx = fmaxf(fmaxf(sc[qs][0][r], sc[qs][1][r]), fmaxf(sc[qs][2][r], sc[qs][3][r]));
#pragma unroll
          for (int d = 8; d >= 1; d >>= 1) mx = fmaxf(mx, __shfl_xor(mx, d, 64));
          const float mnew = fmaxf(mrun[qs][r], mx);
          const float fs = __expf(mrun[qs][r] - mnew);
          float rs = 0.f;
#pragma unroll
          for (int ks = 0; ks < 4; ++ks) {
            float p = __expf(sc[qs][ks][r] - mnew);
            sc[qs][ks][r] = p; rs += p;
          }
#pragma unroll
          for (int d = 8; d >= 1; d >>= 1) rs += __shfl_xor(rs, d, 64);
          lrun[qs][r] = lrun[qs][r] * fs + rs;
          mrun[qs][r] = mnew;
#pragma unroll
          for (int ds = 0; ds < 4; ++ds) o[qs][ds][r] *= fs;
        }
      // P (C-layout) -> LDS -> A-layout fragments
#pragma unroll
      for (int qs = 0; qs < 2; ++qs)
#pragma unroll
        for (int ks = 0; ks < 4; ++ks)
#pragma unroll
          for (int r = 0; r < 4; ++r)
            Pb[w][qs * 16 + lg * 4 + r][ks * 16 + li] = f2bf(sc[qs][ks][r]);
      s16x8 ap[2][2];
#pragma unroll
      for (int qs = 0; qs < 2; ++qs)
#pragma unroll
        for (int kp = 0; kp < 2; ++kp)
          ap[qs][kp] = *reinterpret_cast<const s16x8*>(&Pb[w][qs * 16 + li][kp * 32 + lg * 8]);
#pragma unroll
      for (int ds = 0; ds < 4; ++ds) {
        const int R = ds * 16 + li;
        const char* vbase = (const char*)&Vb[cur][0] + R * 128;
        const int sw = (R & 7) << 4;
        s16x8 bv0 = *reinterpret_cast<const s16x8*>(vbase + ((lg * 16) ^ sw));
        s16x8 bv1 = *reinterpret_cast<const s16x8*>(vbase + (((64 + lg * 16)) ^ sw));
#pragma unroll
        for (int qs = 0; qs < 2; ++qs) {
          o[qs][ds] = __builtin_amdgcn_mfma_f32_16x16x32_bf16(ap[qs][0], bv0, o[qs][ds], 0, 0, 0);
          o[qs][ds] = __builtin_amdgcn_mfma_f32_16x16x32_bf16(ap[qs][1], bv1, o[qs][ds], 0, 0, 0);
        }
      }
    }
    if (it == nA - 1) {  // phase switch: flush tile A, start tile B
      writeO(q0);
      q0 = tB * 128 + w * 32;
      loadQ(q0);
      resetState();
    }
    kt = ktn;
  }
  writeO(q0);
}

extern "C" void kernel_launch(void* const* d_in, const int* in_sizes, int n_in,
                              void* d_out, int out_size, void* d_ws, size_t ws_size,
                              hipStream_t stream) {
  const float* x  = (const float*)d_in[0];
  const int*  pos = (const int*)d_in[1];
  const float* wq = (const float*)d_in[2];
  const float* wk = (const float*)d_in[3];
  const float* wv = (const float*)d_in[4];
  const float* wo = (const float*)d_in[5];
  float* out = (float*)d_out;

  u16* Wb = (u16*)d_ws;               // 4*NW bf16 (Wq|Wk|Wv|Wo)
  u16* xb = Wb + 4 * (size_t)NW;      // NX bf16
  u16* Qw = xb + (size_t)NX;          // (b,h,s,d)
  u16* Kw = Qw + (size_t)NX;          // (b,h,s,d)
  u16* Vt = Kw + (size_t)NX;          // (b,h,d,s)
  u16* Ab = xb;                       // reuse x-bf16 region for attn output

  convert_all<<<(NX + 4 * NW) / 4 / 256, 256, 0, stream>>>(x, wq, wk, wv, wo, xb, Wb);
  gemm128<0><<<dim3(24, 64), 256, 0, stream>>>(xb, Wb, Qw, Kw, Vt, nullptr);
  rope_qk<<<2 * (BATCH * NH * SEQ * 32) / 256, 256, 0, stream>>>(Qw, Kw, pos);
  attn_kernel<<<512, 256, 0, stream>>>(Qw, Kw, Vt, Ab);
  gemm128<1><<<dim3(8, 64), 256, 0, stream>>>(Ab, Wb + 3 * (size_t)NW, nullptr, nullptr, nullptr, out);
}

// Round 4
// 309.699 us; speedup vs baseline: 2.3026x; 1.2806x over previous
//
#include <hip/hip_runtime.h>
#include <hip/hip_bf16.h>

typedef unsigned short u16;
typedef __attribute__((ext_vector_type(4))) float f32x4;
typedef __attribute__((ext_vector_type(8))) short s16x8;

constexpr int DMODEL = 1024;
constexpr int NH     = 16;
constexpr int DK     = 64;
constexpr int SEQ    = 4096;
constexpr int BATCH  = 2;
constexpr int BS     = BATCH * SEQ;     // 8192
constexpr int NX     = BS * DMODEL;     // 8,388,608
constexpr int NW     = DMODEL * DMODEL; // 1,048,576

__device__ __forceinline__ u16 f2bf(float f) {
  union { float f; unsigned u; } v; v.f = f;
  unsigned r = v.u + 0x7fffu + ((v.u >> 16) & 1u);
  return (u16)(r >> 16);
}
__device__ __forceinline__ float bf2f(u16 h) {
  union { unsigned u; float f; } v; v.u = ((unsigned)h) << 16;
  return v.f;
}
// packed f32x2 -> bf16x2 via v_cvt_pk_bf16_f32 (compiler emits from this API)
__device__ __forceinline__ unsigned pk2(float a, float b) {
  float2 t; t.x = a; t.y = b;
  __hip_bfloat162 h = __float22bfloat162_rn(t);
  return *reinterpret_cast<unsigned*>(&h);
}
__device__ __forceinline__ void gload_lds16(const void* g, void* l) {
  __builtin_amdgcn_global_load_lds(
      (const __attribute__((address_space(1))) void*)g,
      (__attribute__((address_space(3))) void*)l, 16, 0, 0);
}

// ---------------- fp32 -> bf16 conversion for x and W[qkvo] ----------------
__global__ __launch_bounds__(256) void convert_all(
    const float* __restrict__ x, const float* __restrict__ wq,
    const float* __restrict__ wk, const float* __restrict__ wv,
    const float* __restrict__ wo, u16* __restrict__ xb, u16* __restrict__ Wb) {
  int t = blockIdx.x * 256 + threadIdx.x;
  int i = t * 4;
  const float* src; u16* dst;
  if (i < NX) { src = x + i; dst = xb + i; }
  else {
    int j = i - NX; int w = j >> 20; int jj = j & (NW - 1);
    src = (w == 0 ? wq : w == 1 ? wk : w == 2 ? wv : wo) + jj;
    dst = Wb + j;
  }
  float4 v = *reinterpret_cast<const float4*>(src);
  uint2 pk; pk.x = pk2(v.x, v.y); pk.y = pk2(v.z, v.w);
  *reinterpret_cast<uint2*>(dst) = pk;
}

// ---------------- 128x128 bf16 GEMM, C = A * B^T (B rows = output cols) ----
template <int EPI>
__global__ __launch_bounds__(256) void gemm128(
    const u16* __restrict__ A, const u16* __restrict__ B,
    u16* __restrict__ Qw, u16* __restrict__ Kw, u16* __restrict__ Vt,
    float* __restrict__ Co) {
  __shared__ u16 lA[128 * 32];
  __shared__ u16 lB[128 * 32];
  const int tid = threadIdx.x, w = tid >> 6, l = tid & 63;
  const int wr = w >> 1, wc = w & 1;
  const int m0 = blockIdx.y * 128, n0 = blockIdx.x * 128;
  constexpr int K = 1024;
  f32x4 acc[4][4] = {};
  const int li = l & 15, lg = l >> 4;
  const int srow = l >> 2, skc = (l & 3) * 8;
  for (int k0 = 0; k0 < K; k0 += 32) {
    __syncthreads();
#pragma unroll
    for (int cc = 0; cc < 2; ++cc) {
      const int c = 2 * w + cc;
      const int row = c * 16 + srow;
      gload_lds16(A + (size_t)(m0 + row) * K + k0 + skc, &lA[c * 512]);
      gload_lds16(B + (size_t)(n0 + row) * K + k0 + skc, &lB[c * 512]);
    }
    __syncthreads();
    s16x8 af[4], bfr[4];
#pragma unroll
    for (int i = 0; i < 4; ++i)
      af[i] = *reinterpret_cast<const s16x8*>(&lA[(wr * 64 + i * 16 + li) * 32 + lg * 8]);
#pragma unroll
    for (int j = 0; j < 4; ++j)
      bfr[j] = *reinterpret_cast<const s16x8*>(&lB[(wc * 64 + j * 16 + li) * 32 + lg * 8]);
#pragma unroll
    for (int i = 0; i < 4; ++i)
#pragma unroll
      for (int j = 0; j < 4; ++j)
        acc[i][j] = __builtin_amdgcn_mfma_f32_16x16x32_bf16(af[i], bfr[j], acc[i][j], 0, 0, 0);
  }
#pragma unroll
  for (int i = 0; i < 4; ++i) {
    const int mbase = m0 + wr * 64 + i * 16 + lg * 4;
#pragma unroll
    for (int j = 0; j < 4; ++j) {
      const int n = n0 + wc * 64 + j * 16 + li;
      if (EPI == 0) {
        const int which = n >> 10, nn = n & 1023, h = nn >> 6, d = nn & 63;
#pragma unroll
        for (int r = 0; r < 4; ++r) {
          const int m = mbase + r, b = m >> 12, s = m & (SEQ - 1);
          const int bh = b * NH + h;
          const u16 val = f2bf(acc[i][j][r]);
          if (which == 0)      Qw[((size_t)bh * SEQ + s) * DK + d] = val;
          else if (which == 1) Kw[((size_t)bh * SEQ + s) * DK + d] = val;
          else                 Vt[((size_t)bh * DK + d) * SEQ + s] = val;
        }
      } else {
#pragma unroll
        for (int r = 0; r < 4; ++r)
          Co[(size_t)(mbase + r) * DMODEL + n] = acc[i][j][r];
      }
    }
  }
}

// ---------------- RoPE in-place on Q and K; Q additionally scaled by 1/8 ---
__global__ __launch_bounds__(256) void rope_qk(u16* __restrict__ Qw, u16* __restrict__ Kw,
                                               const int* __restrict__ pos) {
  const int TOT = BATCH * NH * SEQ * 32;  // pairs per tensor
  int t = blockIdx.x * 256 + threadIdx.x;
  const bool isQ = (t < TOT);
  u16* arr = isQ ? Qw : Kw;
  int p = isQ ? t : t - TOT;
  const int i = p & 31;
  const int s = (p >> 5) & (SEQ - 1);
  const int bh = p >> 17;
  const float inv = expf(-(float)i * 0.28782313662425574f);
  const float ang = (float)pos[s] * inv;
  float sn, cs;
  sincosf(ang, &sn, &cs);
  const float sc = isQ ? 0.125f : 1.0f;  // fold softmax scale into Q
  u16* ptr = arr + ((size_t)bh * SEQ + s) * DK + 2 * i;
  unsigned v = *reinterpret_cast<unsigned*>(ptr);
  float xe = bf2f((u16)(v & 0xffffu)), xo = bf2f((u16)(v >> 16));
  float oe = (xe * cs - xo * sn) * sc;
  float oo = (xe * sn + xo * cs) * sc;
  *reinterpret_cast<unsigned*>(ptr) = pk2(oe, oo);
}

// ---------------- causal flash attention, swapped-operand softmax ----------
// 512 blocks, paired q-tiles (heavy+light) for uniform duration. Swapped
// MFMAs: sc=mfma(K,Q) -> P[k][q] with q=li lane-local (in-lane row reduce,
// 2 shfl); o=mfma(V,P) -> O[d][q], rescale/normalize lane-local. P routed
// through per-wave LDS (stride 76, conflict-free) as cvt_pk-packed b64.
__global__ __launch_bounds__(256) void attn_kernel(
    const u16* __restrict__ Qw, const u16* __restrict__ Kw,
    const u16* __restrict__ Vt, u16* __restrict__ Ob) {
  __shared__ __align__(16) u16 Kb[2][4096];
  __shared__ __align__(16) u16 Vb[2][4096];
  __shared__ __align__(16) u16 Pb[4][32][76];
  const int tid = threadIdx.x, w = tid >> 6, l = tid & 63;
  const int li = l & 15, lg = l >> 4;
  const int id = blockIdx.x;
  const int g = (id & 7) * 64 + (id >> 3);    // XCD-chunked (64 blocks/XCD)
  const int bh = g >> 4;                      // 4 heads per XCD chunk
  const int j  = g & 15;                      // pair index
  const int tA = 31 - j, tB = j;              // heavy first
  const int nA = 2 * tA + 2, nB = 2 * tB + 2; // 66 total iterations
  const u16* Qh = Qw + (size_t)bh * SEQ * DK;
  const u16* Kh = Kw + (size_t)bh * SEQ * DK;
  const u16* Vh = Vt + (size_t)bh * DK * SEQ;
  const int b = bh >> 4, h = bh & 15;

  const int row0  = tid >> 3;
  const int scol0 = ((tid & 7) * 16) ^ ((row0 & 7) << 4);

  s16x8 aq[2][2];
  f32x4 o[2][4];
  float mrun[2], lrun[2];

  auto loadQ = [&](int q0) {
#pragma unroll
    for (int qs = 0; qs < 2; ++qs)
#pragma unroll
      for (int ds = 0; ds < 2; ++ds)
        aq[qs][ds] = *reinterpret_cast<const s16x8*>(
            &Qh[(size_t)(q0 + qs * 16 + li) * DK + ds * 32 + lg * 8]);
  };
  auto resetState = [&]() {
#pragma unroll
    for (int qs = 0; qs < 2; ++qs) {
      mrun[qs] = -1e30f; lrun[qs] = 0.f;
#pragma unroll
      for (int ds = 0; ds < 4; ++ds) o[qs][ds] = f32x4{0.f, 0.f, 0.f, 0.f};
    }
  };
  auto writeO = [&](int q0) {
#pragma unroll
    for (int qs = 0; qs < 2; ++qs) {
      const float inv = 1.f / lrun[qs];
      const int s = q0 + qs * 16 + li;
      u16* orow = Ob + ((size_t)(b * SEQ + s)) * DMODEL + h * DK;
#pragma unroll
      for (int ds = 0; ds < 4; ++ds) {
        uint2 pkv;
        pkv.x = pk2(o[qs][ds][0] * inv, o[qs][ds][1] * inv);
        pkv.y = pk2(o[qs][ds][2] * inv, o[qs][ds][3] * inv);
        *reinterpret_cast<uint2*>(orow + ds * 16 + lg * 4) = pkv;
      }
    }
  };
  auto stage = [&](int buf, int kt) {
    const char* ksrc = (const char*)Kh + (size_t)(kt + row0) * 128 + scol0;
    char* kdst = (char*)&Kb[buf][0] + (size_t)w * 1024;
    gload_lds16(ksrc, kdst);
    gload_lds16(ksrc + 32 * 128, kdst + 4096);
    const char* vsrc = (const char*)Vh + (size_t)row0 * (SEQ * 2) + kt * 2 + scol0;
    char* vdst = (char*)&Vb[buf][0] + (size_t)w * 1024;
    gload_lds16(vsrc, vdst);
    gload_lds16(vsrc + (size_t)32 * SEQ * 2, vdst + 4096);
  };

  int q0 = tA * 128 + w * 32;
  loadQ(q0);
  resetState();
  stage(0, 0);
  int kt = 0;
  const int ntot = nA + nB;
  for (int it = 0; it < ntot; ++it) {
    asm volatile("s_waitcnt vmcnt(0)" ::: "memory");  // current buf staged
    __builtin_amdgcn_s_barrier();
    __builtin_amdgcn_sched_barrier(0);
    const int itn = it + 1;
    const int ktn = (itn < nA) ? 64 * itn : (itn < ntot ? 64 * (itn - nA) : 0);
    stage(itn & 1, ktn);
    if (kt < q0 + 32) {  // skip fully-masked tiles for this wave
      const int cur = it & 1;
      // ---- QK^T (swapped): sc[qs][ks] rows k=kt+ks*16+lg*4+r, col q=q0+qs*16+li
      f32x4 sc[2][4];
      __builtin_amdgcn_s_setprio(1);
#pragma unroll
      for (int ks = 0; ks < 4; ++ks) {
        const int R = ks * 16 + li;
        const char* kbase = (const char*)&Kb[cur][0] + R * 128;
        const int sw = (R & 7) << 4;
        s16x8 bk0 = *reinterpret_cast<const s16x8*>(kbase + ((lg * 16) ^ sw));
        s16x8 bk1 = *reinterpret_cast<const s16x8*>(kbase + (((64 + lg * 16)) ^ sw));
#pragma unroll
        for (int qs = 0; qs < 2; ++qs) {
          f32x4 z = {0.f, 0.f, 0.f, 0.f};
          z = __builtin_amdgcn_mfma_f32_16x16x32_bf16(bk0, aq[qs][0], z, 0, 0, 0);
          z = __builtin_amdgcn_mfma_f32_16x16x32_bf16(bk1, aq[qs][1], z, 0, 0, 0);
          sc[qs][ks] = z;
        }
      }
      __builtin_amdgcn_s_setprio(0);
      if (kt + 63 > q0) {  // causal mask: k > q
#pragma unroll
        for (int qs = 0; qs < 2; ++qs)
#pragma unroll
          for (int ks = 0; ks < 4; ++ks)
#pragma unroll
            for (int r = 0; r < 4; ++r)
              if (kt + ks * 16 + lg * 4 + r > q0 + qs * 16 + li) sc[qs][ks][r] = -1e30f;
      }
      // ---- online softmax, lane-local per q
      float pm[2];
#pragma unroll
      for (int qs = 0; qs < 2; ++qs) {
        float a0 = fmaxf(fmaxf(sc[qs][0][0], sc[qs][0][1]), fmaxf(sc[qs][0][2], sc[qs][0][3]));
        float a1 = fmaxf(fmaxf(sc[qs][1][0], sc[qs][1][1]), fmaxf(sc[qs][1][2], sc[qs][1][3]));
        float a2 = fmaxf(fmaxf(sc[qs][2][0], sc[qs][2][1]), fmaxf(sc[qs][2][2], sc[qs][2][3]));
        float a3 = fmaxf(fmaxf(sc[qs][3][0], sc[qs][3][1]), fmaxf(sc[qs][3][2], sc[qs][3][3]));
        float m16 = fmaxf(fmaxf(a0, a1), fmaxf(a2, a3));
        m16 = fmaxf(m16, __shfl_xor(m16, 16, 64));
        m16 = fmaxf(m16, __shfl_xor(m16, 32, 64));
        pm[qs] = m16;
      }
      const bool ok = (pm[0] <= mrun[0] + 8.f) && (pm[1] <= mrun[1] + 8.f);
      if (!__all(ok)) {  // rescale path (rare after warm-up: defer-max)
#pragma unroll
        for (int qs = 0; qs < 2; ++qs) {
          const float mn = fmaxf(mrun[qs], pm[qs]);
          const float fs = __expf(mrun[qs] - mn);
          mrun[qs] = mn; lrun[qs] *= fs;
#pragma unroll
          for (int ds = 0; ds < 4; ++ds) o[qs][ds] *= fs;
        }
      }
#pragma unroll
      for (int qs = 0; qs < 2; ++qs) {
        float rs = 0.f;
#pragma unroll
        for (int ks = 0; ks < 4; ++ks)
#pragma unroll
          for (int r = 0; r < 4; ++r) {
            const float p = __expf(sc[qs][ks][r] - mrun[qs]);
            sc[qs][ks][r] = p; rs += p;
          }
        rs += __shfl_xor(rs, 16, 64);
        rs += __shfl_xor(rs, 32, 64);
        lrun[qs] += rs;
        // pack P rows k=ks*16+lg*4..+3 for q-row (qs*16+li) -> b64 writes
#pragma unroll
        for (int ks = 0; ks < 4; ++ks) {
          uint2 pw;
          pw.x = pk2(sc[qs][ks][0], sc[qs][ks][1]);
          pw.y = pk2(sc[qs][ks][2], sc[qs][ks][3]);
          *reinterpret_cast<uint2*>(&Pb[w][qs * 16 + li][ks * 16 + lg * 4]) = pw;
        }
      }
      // ---- PV (swapped): o[qs][ds] rows d=ds*16+lg*4+r, col q=li
      s16x8 ap[2][2];
#pragma unroll
      for (int qs = 0; qs < 2; ++qs)
#pragma unroll
        for (int kp = 0; kp < 2; ++kp)
          ap[qs][kp] = *reinterpret_cast<const s16x8*>(&Pb[w][qs * 16 + li][kp * 32 + lg * 8]);
      __builtin_amdgcn_s_setprio(1);
#pragma unroll
      for (int ds = 0; ds < 4; ++ds) {
        const int R = ds * 16 + li;
        const char* vbase = (const char*)&Vb[cur][0] + R * 128;
        const int sw = (R & 7) << 4;
        s16x8 bv0 = *reinterpret_cast<const s16x8*>(vbase + ((lg * 16) ^ sw));
        s16x8 bv1 = *reinterpret_cast<const s16x8*>(vbase + (((64 + lg * 16)) ^ sw));
#pragma unroll
        for (int qs = 0; qs < 2; ++qs) {
          o[qs][ds] = __builtin_amdgcn_mfma_f32_16x16x32_bf16(bv0, ap[qs][0], o[qs][ds], 0, 0, 0);
          o[qs][ds] = __builtin_amdgcn_mfma_f32_16x16x32_bf16(bv1, ap[qs][1], o[qs][ds], 0, 0, 0);
        }
      }
      __builtin_amdgcn_s_setprio(0);
    }
    if (it == nA - 1) {  // phase switch: flush tile A, start tile B
      writeO(q0);
      q0 = tB * 128 + w * 32;
      loadQ(q0);
      resetState();
    }
    kt = ktn;
  }
  writeO(q0);
}

extern "C" void kernel_launch(void* const* d_in, const int* in_sizes, int n_in,
                              void* d_out, int out_size, void* d_ws, size_t ws_size,
                              hipStream_t stream) {
  const float* x  = (const float*)d_in[0];
  const int*  pos = (const int*)d_in[1];
  const float* wq = (const float*)d_in[2];
  const float* wk = (const float*)d_in[3];
  const float* wv = (const float*)d_in[4];
  const float* wo = (const float*)d_in[5];
  float* out = (float*)d_out;

  u16* Wb = (u16*)d_ws;               // 4*NW bf16 (Wq|Wk|Wv|Wo)
  u16* xb = Wb + 4 * (size_t)NW;      // NX bf16
  u16* Qw = xb + (size_t)NX;          // (b,h,s,d)
  u16* Kw = Qw + (size_t)NX;          // (b,h,s,d)
  u16* Vt = Kw + (size_t)NX;          // (b,h,d,s)
  u16* Ab = xb;                       // reuse x-bf16 region for attn output

  convert_all<<<(NX + 4 * NW) / 4 / 256, 256, 0, stream>>>(x, wq, wk, wv, wo, xb, Wb);
  gemm128<0><<<dim3(24, 64), 256, 0, stream>>>(xb, Wb, Qw, Kw, Vt, nullptr);
  rope_qk<<<2 * (BATCH * NH * SEQ * 32) / 256, 256, 0, stream>>>(Qw, Kw, pos);
  attn_kernel<<<512, 256, 0, stream>>>(Qw, Kw, Vt, Ab);
  gemm128<1><<<dim3(8, 64), 256, 0, stream>>>(Ab, Wb + 3 * (size_t)NW, nullptr, nullptr, nullptr, out);
}